// Round 1
// baseline (344.133 us; speedup 1.0000x reference)
//
#include <hip/hip_runtime.h>

#define B_ 8
#define N_ 2048
#define FIN_ 512
#define FOUT_ 512

typedef __attribute__((ext_vector_type(8))) short short8;
typedef __attribute__((ext_vector_type(4))) float floatx4;
typedef __attribute__((ext_vector_type(4))) unsigned short ushortx4;
typedef __attribute__((ext_vector_type(8))) unsigned short ushortx8;

__device__ inline unsigned short f2bf(float f) {
    union { float f; unsigned int u; } x; x.f = f;
    unsigned int r = x.u + 0x7FFFu + ((x.u >> 16) & 1u);  // RNE
    return (unsigned short)(r >> 16);
}

__device__ inline void glds16(const void* g, void* l) {
    __builtin_amdgcn_global_load_lds(
        (const __attribute__((address_space(1))) void*)g,
        (__attribute__((address_space(3))) void*)l, 16, 0, 0);
}

// --- 1) dinv[b*N+i] = rsqrt(1 + sum_j A[b,i,j]) ------------------------------
__global__ __launch_bounds__(256) void degree_kernel(const float* __restrict__ A,
                                                     float* __restrict__ dinv) {
    int row = blockIdx.x;                 // b*N + i
    const float4* A4 = (const float4*)(A + (size_t)row * N_);
    int t = threadIdx.x;
    float4 v0 = A4[t];
    float4 v1 = A4[t + 256];
    float s = v0.x + v0.y + v0.z + v0.w + v1.x + v1.y + v1.z + v1.w;
#pragma unroll
    for (int off = 32; off > 0; off >>= 1) s += __shfl_down(s, off, 64);
    __shared__ float red[4];
    if ((t & 63) == 0) red[t >> 6] = s;
    __syncthreads();
    if (t == 0) dinv[row] = rsqrtf(red[0] + red[1] + red[2] + red[3] + 1.0f);
}

// --- 2) Lbf[b,i,j] = bf16((A[b,i,j] + (i==j)) * dinv_i * dinv_j) -------------
__global__ __launch_bounds__(256) void scaleL_kernel(const float* __restrict__ A,
                                                     const float* __restrict__ dinv,
                                                     unsigned short* __restrict__ Lbf) {
    size_t e0 = ((size_t)blockIdx.x * 256 + threadIdx.x) * 8;
    int b   = (int)(e0 >> 22);            // N*N = 2^22
    int rem = (int)(e0 & ((1u << 22) - 1));
    int i   = rem >> 11;                  // N = 2^11
    int j0  = rem & 2047;
    float di = dinv[b * N_ + i];
    const float* dj = dinv + b * N_ + j0;
    float4 a0 = *(const float4*)(A + e0);
    float4 a1 = *(const float4*)(A + e0 + 4);
    float4 d0 = *(const float4*)(dj);
    float4 d1 = *(const float4*)(dj + 4);
    float av[8] = {a0.x, a0.y, a0.z, a0.w, a1.x, a1.y, a1.z, a1.w};
    float dv[8] = {d0.x, d0.y, d0.z, d0.w, d1.x, d1.y, d1.z, d1.w};
    int dd = i - j0;
    if (dd >= 0 && dd < 8) av[dd] += 1.0f;
    ushortx8 p;
#pragma unroll
    for (int r = 0; r < 8; ++r) p[r] = f2bf(av[r] * di * dv[r]);
    *(ushortx8*)(Lbf + e0) = p;
}

// --- 3a) X -> bf16 -----------------------------------------------------------
__global__ __launch_bounds__(256) void castX_kernel(const float* __restrict__ X,
                                                    unsigned short* __restrict__ Xbf) {
    size_t e0 = ((size_t)blockIdx.x * 256 + threadIdx.x) * 8;
    float4 a0 = *(const float4*)(X + e0);
    float4 a1 = *(const float4*)(X + e0 + 4);
    float av[8] = {a0.x, a0.y, a0.z, a0.w, a1.x, a1.y, a1.z, a1.w};
    ushortx8 p;
#pragma unroll
    for (int r = 0; r < 8; ++r) p[r] = f2bf(av[r]);
    *(ushortx8*)(Xbf + e0) = p;
}

// --- 3b) Wt[n][k] = bf16(W[k][n]) -------------------------------------------
__global__ __launch_bounds__(256) void transposeW_kernel(const float* __restrict__ W,
                                                         unsigned short* __restrict__ Wt) {
    __shared__ float tile[32][33];
    int bx = blockIdx.x * 32;   // F_OUT block
    int by = blockIdx.y * 32;   // F_IN block
    int tx = threadIdx.x, ty = threadIdx.y;   // 32 x 8
#pragma unroll
    for (int r = 0; r < 32; r += 8)
        tile[ty + r][tx] = W[(size_t)(by + ty + r) * FOUT_ + bx + tx];
    __syncthreads();
#pragma unroll
    for (int r = 0; r < 32; r += 8)
        Wt[(size_t)(bx + ty + r) * FIN_ + by + tx] = f2bf(tile[tx][ty + r]);
}

// --- 4/5) C = A(MxK, bf16 row-major) * B^T(NxK, bf16 row-major) --------------
// m97 structure: 128x128 block tile, 4 waves, each wave 64x64 = 4x4 MFMA
// 16x16x32 tiles, BK=32, global_load_lds width-16 staging, 2-barrier K-loop.
// EPI=0: fp32 C [ldc=FOUT_], batched via blockIdx.z.
// EPI=1: bf16 transposed write XwT[b][col][node] + bias (feeds GEMM2 as B^T).
template <int EPI>
__global__ __launch_bounds__(256) void gemm_bt_kernel(
    const unsigned short* __restrict__ Abase,
    const unsigned short* __restrict__ Btbase,
    void* __restrict__ outp, const float* __restrict__ bias,
    int K, int lda, int ldb, size_t strideA, size_t strideB) {
    __shared__ __align__(16) char smem[16384];
    char* As = smem;          // 128 x 32 bf16 = 8 KB
    char* Bs = smem + 8192;   // 128 x 32 bf16 = 8 KB

    int t = threadIdx.x;
    int lane = t & 63;
    int wave = t >> 6;
    int wr = wave >> 1, wc = wave & 1;
    int q = lane >> 4, m = lane & 15;
    int n0 = blockIdx.x * 128;
    int m0 = blockIdx.y * 128;
    int batch = blockIdx.z;
    const unsigned short* Ab = Abase + (size_t)batch * strideA;
    const unsigned short* Bb = Btbase + (size_t)batch * strideB;

    // staging: thread t stages 16B at LDS byte offset issue*4096 + t*16
    int e0 = t * 8;               // bf16 elements into tile
    int srow = e0 >> 5;           // 32 elems per tile row
    int skk = e0 & 31;

    floatx4 acc[4][4];
#pragma unroll
    for (int mi = 0; mi < 4; ++mi)
#pragma unroll
        for (int ni = 0; ni < 4; ++ni)
            acc[mi][ni] = (floatx4){0.f, 0.f, 0.f, 0.f};

    const unsigned short* gA  = Ab + (size_t)(m0 + srow) * lda + skk;
    const unsigned short* gA2 = Ab + (size_t)(m0 + srow + 64) * lda + skk;
    const unsigned short* gB  = Bb + (size_t)(n0 + srow) * ldb + skk;
    const unsigned short* gB2 = Bb + (size_t)(n0 + srow + 64) * ldb + skk;
    char* lA  = As + wave * 1024;          // wave-uniform LDS bases
    char* lA2 = As + 4096 + wave * 1024;
    char* lB  = Bs + wave * 1024;
    char* lB2 = Bs + 4096 + wave * 1024;

    int kiters = K >> 5;
    for (int kt = 0; kt < kiters; ++kt) {
        glds16(gA, lA);
        glds16(gA2, lA2);
        glds16(gB, lB);
        glds16(gB2, lB2);
        gA += 32; gA2 += 32; gB += 32; gB2 += 32;
        __syncthreads();   // drains vmcnt: staging complete

        short8 af[4], bfr[4];
#pragma unroll
        for (int mi = 0; mi < 4; ++mi) {
            int row = wr * 64 + mi * 16 + m;      // A[m=lane&15][k=q*8+j]
            af[mi] = *(const short8*)(As + row * 64 + q * 16);
        }
#pragma unroll
        for (int ni = 0; ni < 4; ++ni) {
            int row = wc * 64 + ni * 16 + m;      // Bt[n=lane&15][k=q*8+j]
            bfr[ni] = *(const short8*)(Bs + row * 64 + q * 16);
        }
#pragma unroll
        for (int mi = 0; mi < 4; ++mi)
#pragma unroll
            for (int ni = 0; ni < 4; ++ni)
                acc[mi][ni] = __builtin_amdgcn_mfma_f32_16x16x32_bf16(
                    af[mi], bfr[ni], acc[mi][ni], 0, 0, 0);
        __syncthreads();   // LDS reuse next iter
    }

    // C/D layout: col = lane&15, row = (lane>>4)*4 + reg   [m89/m91-verified]
    if (EPI == 0) {
        float* C = (float*)outp + (size_t)batch * ((size_t)N_ * FOUT_);
#pragma unroll
        for (int mi = 0; mi < 4; ++mi) {
            int rowb = m0 + wr * 64 + mi * 16 + q * 4;
#pragma unroll
            for (int ni = 0; ni < 4; ++ni) {
                int col = n0 + wc * 64 + ni * 16 + m;
#pragma unroll
                for (int r = 0; r < 4; ++r)
                    C[(size_t)(rowb + r) * FOUT_ + col] = acc[mi][ni][r];
            }
        }
    } else {
        unsigned short* XwT = (unsigned short*)outp;  // [B][FOUT][N] bf16
#pragma unroll
        for (int mi = 0; mi < 4; ++mi) {
            int rowb = m0 + wr * 64 + mi * 16 + q * 4;  // 4 consecutive M rows
            int bb = rowb >> 11;                        // batch (tile within one batch)
            int node = rowb & 2047;
#pragma unroll
            for (int ni = 0; ni < 4; ++ni) {
                int col = n0 + wc * 64 + ni * 16 + m;
                float bv = bias[col];
                ushortx4 pk;
#pragma unroll
                for (int r = 0; r < 4; ++r) pk[r] = f2bf(acc[mi][ni][r] + bv);
                *(ushortx4*)(XwT + ((size_t)bb * FOUT_ + col) * N_ + node) = pk;
            }
        }
    }
}

extern "C" void kernel_launch(void* const* d_in, const int* in_sizes, int n_in,
                              void* d_out, int out_size, void* d_ws, size_t ws_size,
                              hipStream_t stream) {
    const float* X    = (const float*)d_in[0];   // [8,2048,512]
    const float* A    = (const float*)d_in[1];   // [8,2048,2048]
    const float* W    = (const float*)d_in[2];   // [512,512]
    const float* bias = (const float*)d_in[3];   // [512]
    float* out = (float*)d_out;                  // [8,2048,512] fp32
    char* ws = (char*)d_ws;

    float* dinv          = (float*)(ws);                              // 64 KB
    unsigned short* Xbf  = (unsigned short*)(ws + (1u << 16));        // 16 MB
    unsigned short* Wt   = (unsigned short*)(ws + (1u << 16) + 16777216u);           // 512 KB
    unsigned short* XwT  = (unsigned short*)(ws + (1u << 16) + 16777216u + 524288u); // 16 MB
    unsigned short* Lbf  = (unsigned short*)(ws + (1u << 16) + 16777216u + 524288u + 16777216u); // 64 MB

    degree_kernel<<<B_ * N_, 256, 0, stream>>>(A, dinv);
    scaleL_kernel<<<(B_ * (size_t)N_ * N_) / 2048, 256, 0, stream>>>(A, dinv, Lbf);
    castX_kernel<<<((size_t)B_ * N_ * FIN_) / 2048, 256, 0, stream>>>(X, Xbf);
    transposeW_kernel<<<dim3(FOUT_ / 32, FIN_ / 32), dim3(32, 8), 0, stream>>>(W, Wt);

    // x^T = (Xbf @ W + b)^T  -> XwT [B][FOUT][N] bf16
    gemm_bt_kernel<1><<<dim3(FOUT_ / 128, (B_ * N_) / 128, 1), 256, 0, stream>>>(
        Xbf, Wt, (void*)XwT, bias, FIN_, FIN_, FIN_, 0, 0);

    // out[b] = Lbf[b] @ x[b]   (B^T = XwT[b])
    gemm_bt_kernel<0><<<dim3(FOUT_ / 128, N_ / 128, B_), 256, 0, stream>>>(
        Lbf, XwT, (void*)out, nullptr, N_, N_, N_, (size_t)N_ * N_, (size_t)FOUT_ * N_);
}